// Round 6
// baseline (733.565 us; speedup 1.0000x reference)
//
#include <hip/hip_runtime.h>

#define NN 50000
#define EE 800000
#define ET 850000   // EE + NN self loops
#define HH 4
#define CC 64
#define FDIM 256    // HH*CC

#define SCAN_BLK 512
#define SCAN_NB ((NN + SCAN_BLK - 1) / SCAN_BLK)   // 98

typedef unsigned short ushort;
typedef __bf16 bf16x8 __attribute__((ext_vector_type(8)));
typedef float floatx4 __attribute__((ext_vector_type(4)));
typedef ushort ushort8v __attribute__((ext_vector_type(8)));
struct ushort4s { ushort x, y, z, w; };

__device__ __forceinline__ ushort f2bf(float f) {
  union { float f; unsigned u; } v; v.f = f;
  unsigned r = v.u + 0x7fffu + ((v.u >> 16) & 1u);  // RNE
  return (ushort)(r >> 16);
}
__device__ __forceinline__ float bf2f(ushort u) {
  return __uint_as_float(((unsigned)u) << 16);
}

// ---------- edge-index dtype handling (int32 vs int64 at runtime) ----------
__device__ __forceinline__ int get_edge(const void* p, int is64, long long idx) {
  if (is64) return (int)((const long long*)p)[idx];
  return ((const int*)p)[idx];
}

__global__ void detect_kernel(const unsigned int* p, int* flag) {
  // int64 with values < 50000 => every odd 32-bit word is 0
  __shared__ unsigned red[256];
  int t = threadIdx.x;
  unsigned o = 0;
  for (int i = 0; i < 4; i++) o |= p[(t * 4 + i) * 2 + 1];
  red[t] = o;
  __syncthreads();
  for (int s = 128; s > 0; s >>= 1) {
    if (t < s) red[t] |= red[t + s];
    __syncthreads();
  }
  if (t == 0) *flag = (red[0] == 0) ? 1 : 0;
}

// ---------- CSR build over dst ----------
__global__ void degree_kernel(const void* eidx, const int* flag, int* deg) {
  int k = blockIdx.x * blockDim.x + threadIdx.x;
  if (k >= ET) return;
  int is64 = *flag;
  int dst = (k < EE) ? get_edge(eidx, is64, (long long)EE + k) : (k - EE);
  atomicAdd(&deg[dst], 1);
}

__global__ __launch_bounds__(SCAN_BLK) void scan1_kernel(const int* __restrict__ deg,
                                                         int* __restrict__ rowptr,
                                                         int* __restrict__ bsum) {
  __shared__ int sm[SCAN_BLK];
  int t = threadIdx.x;
  int i = blockIdx.x * SCAN_BLK + t;
  int v = (i < NN) ? deg[i] : 0;
  sm[t] = v;
  __syncthreads();
#pragma unroll
  for (int o = 1; o < SCAN_BLK; o <<= 1) {
    int u = (t >= o) ? sm[t - o] : 0;
    __syncthreads();
    sm[t] += u;
    __syncthreads();
  }
  if (i < NN) rowptr[i] = sm[t] - v;                 // local exclusive
  if (t == SCAN_BLK - 1) bsum[blockIdx.x] = sm[t];   // block total
}

__global__ __launch_bounds__(128) void scan2_kernel(const int* __restrict__ bsum,
                                                    int* __restrict__ boff,
                                                    int* __restrict__ rowptr) {
  __shared__ int sm[128];
  int t = threadIdx.x;
  int v = (t < SCAN_NB) ? bsum[t] : 0;
  sm[t] = v;
  __syncthreads();
#pragma unroll
  for (int o = 1; o < 128; o <<= 1) {
    int u = (t >= o) ? sm[t - o] : 0;
    __syncthreads();
    sm[t] += u;
    __syncthreads();
  }
  if (t < SCAN_NB) boff[t] = sm[t] - v;  // exclusive block offset
  if (t == 0) rowptr[NN] = ET;
}

__global__ __launch_bounds__(SCAN_BLK) void scan3_kernel(int* __restrict__ rowptr,
                                                         int* __restrict__ cursor,
                                                         const int* __restrict__ boff) {
  int i = blockIdx.x * SCAN_BLK + threadIdx.x;
  if (i >= NN) return;
  int v = rowptr[i] + boff[blockIdx.x];
  rowptr[i] = v;
  cursor[i] = v;
}

__global__ void fill_kernel(const void* eidx, const int* flag, int* cursor, int* csr_src) {
  int k = blockIdx.x * blockDim.x + threadIdx.x;
  if (k >= ET) return;
  int is64 = *flag;
  int src, dst;
  if (k < EE) {
    src = get_edge(eidx, is64, k);
    dst = get_edge(eidx, is64, (long long)EE + k);
  } else {
    src = dst = k - EE;
  }
  int pos = atomicAdd(&cursor[dst], 1);
  csr_src[pos] = src;
}

// ---------- dtype conversions ----------
__global__ void conv_x_kernel(const float* __restrict__ x, ushort* __restrict__ xb) {
  int i = blockIdx.x * 256 + threadIdx.x;
  float4 v = ((const float4*)x)[i];
  ushort4s o;
  o.x = f2bf(v.x); o.y = f2bf(v.y); o.z = f2bf(v.z); o.w = f2bf(v.w);
  ((ushort4s*)xb)[i] = o;
}

// all three weight transposes in one dispatch (grid.y selects the matrix)
__global__ void conv_w_kernel(const float* __restrict__ W0, const float* __restrict__ W1,
                              const float* __restrict__ W2,
                              ushort* __restrict__ T0, ushort* __restrict__ T1,
                              ushort* __restrict__ T2) {
  const float* W = (blockIdx.y == 0) ? W0 : (blockIdx.y == 1) ? W1 : W2;
  ushort* Wt = (blockIdx.y == 0) ? T0 : (blockIdx.y == 1) ? T1 : T2;
  int idx = blockIdx.x * 256 + threadIdx.x;  // 65536
  int k = idx >> 8, n = idx & 255;
  Wt[n * 256 + k] = f2bf(W[idx]);  // transpose: Wt[n][k]
}

// ---------- bf16 MFMA GEMM + fused attention-logit partials ----------
// C[M,256] = A[M,256] @ B[256,256] (B given transposed).
// Epilogue: s[n,h] += sum_c h[n,h*64+c]*as[h,c] accumulated via atomics from
// the f32 MFMA accumulators (block covers 128 of the 256 cols -> 2 hits/address).
__global__ __launch_bounds__(256) void gemm_bf16(const ushort* __restrict__ A,
                                                 const ushort* __restrict__ Bt,
                                                 ushort* __restrict__ C,
                                                 const float* __restrict__ as_,
                                                 const float* __restrict__ ad_,
                                                 float* __restrict__ s_arr,
                                                 float* __restrict__ d_arr) {
  __shared__ ushort As[8 * 512];
  __shared__ ushort Bs[8 * 512];
  int tid = threadIdx.x, w = tid >> 6, l = tid & 63;
  int brow0 = blockIdx.x * 128, bcol0 = blockIdx.y * 128;
  int lm = l & 15, lk = (l >> 4) * 8;
  int s0 = 2 * w, s1 = 2 * w + 1;
  int ar0 = min(brow0 + s0 * 16 + lm, NN - 1);
  int ar1 = min(brow0 + s1 * 16 + lm, NN - 1);
  const ushort* ag0 = A + (size_t)ar0 * 256 + lk;
  const ushort* ag1 = A + (size_t)ar1 * 256 + lk;
  const ushort* bg0 = Bt + (size_t)(bcol0 + s0 * 16 + lm) * 256 + lk;
  const ushort* bg1 = Bt + (size_t)(bcol0 + s1 * 16 + lm) * 256 + lk;

  floatx4 acc[4][4];
#pragma unroll
  for (int i = 0; i < 4; i++)
#pragma unroll
    for (int j = 0; j < 4; j++) acc[i][j] = floatx4{0.f, 0.f, 0.f, 0.f};

  int wm = (w >> 1) * 4, wn = (w & 1) * 4;

  for (int k0 = 0; k0 < 256; k0 += 32) {
    ushort8v a0 = *(const ushort8v*)(ag0 + k0);
    ushort8v a1 = *(const ushort8v*)(ag1 + k0);
    ushort8v b0 = *(const ushort8v*)(bg0 + k0);
    ushort8v b1 = *(const ushort8v*)(bg1 + k0);
    *(ushort8v*)&As[s0 * 512 + l * 8] = a0;
    *(ushort8v*)&As[s1 * 512 + l * 8] = a1;
    *(ushort8v*)&Bs[s0 * 512 + l * 8] = b0;
    *(ushort8v*)&Bs[s1 * 512 + l * 8] = b1;
    __syncthreads();
    bf16x8 af[4], bfr[4];
#pragma unroll
    for (int i = 0; i < 4; i++) af[i] = *(const bf16x8*)&As[(wm + i) * 512 + l * 8];
#pragma unroll
    for (int j = 0; j < 4; j++) bfr[j] = *(const bf16x8*)&Bs[(wn + j) * 512 + l * 8];
#pragma unroll
    for (int i = 0; i < 4; i++)
#pragma unroll
      for (int j = 0; j < 4; j++)
        acc[i][j] = __builtin_amdgcn_mfma_f32_16x16x32_bf16(af[i], bfr[j], acc[i][j], 0, 0, 0);
    __syncthreads();
  }

  int quad = l >> 4;
  // ----- C store (row r0+r, col bcol0+(wn+j)*16+lm) -----
#pragma unroll
  for (int i = 0; i < 4; i++) {
    int r0 = brow0 + (wm + i) * 16 + quad * 4;
#pragma unroll
    for (int j = 0; j < 4; j++) {
      int col = bcol0 + (wn + j) * 16 + lm;
#pragma unroll
      for (int r = 0; r < 4; r++) {
        int row = r0 + r;
        if (row < NN) C[(size_t)row * 256 + col] = f2bf(acc[i][j][r]);
      }
    }
  }
  // ----- fused s/d partials -----
  float asv[4], adv[4];
#pragma unroll
  for (int j = 0; j < 4; j++) {
    int col = bcol0 + (wn + j) * 16 + lm;
    asv[j] = as_[col];
    adv[j] = ad_[col];
  }
  int head = (bcol0 >> 6) + (wn >> 2);  // wn in {0,4} -> two heads per block
#pragma unroll
  for (int i = 0; i < 4; i++) {
#pragma unroll
    for (int r = 0; r < 4; r++) {
      float sp = acc[i][0][r] * asv[0] + acc[i][1][r] * asv[1] +
                 acc[i][2][r] * asv[2] + acc[i][3][r] * asv[3];
      float dp = acc[i][0][r] * adv[0] + acc[i][1][r] * adv[1] +
                 acc[i][2][r] * adv[2] + acc[i][3][r] * adv[3];
      sp += __shfl_xor(sp, 1); dp += __shfl_xor(dp, 1);
      sp += __shfl_xor(sp, 2); dp += __shfl_xor(dp, 2);
      sp += __shfl_xor(sp, 4); dp += __shfl_xor(dp, 4);
      sp += __shfl_xor(sp, 8); dp += __shfl_xor(dp, 8);
      if (lm == 0) {
        int row = brow0 + (wm + i) * 16 + quad * 4 + r;
        if (row < NN) {
          atomicAdd(&s_arr[row * HH + head], sp);
          atomicAdd(&d_arr[row * HH + head], dp);
        }
      }
    }
  }
}

// ---------- aggregation: one wave per node, all heads; fused edge softmax ----------
template <bool CONCAT>
__global__ __launch_bounds__(256) void agg_kernel(const ushort* __restrict__ hb,
                                                  const float* __restrict__ s_arr,
                                                  const float* __restrict__ d_arr,
                                                  const int* __restrict__ rowptr,
                                                  const int* __restrict__ csr_src,
                                                  const float* __restrict__ bias,
                                                  void* __restrict__ outp) {
  int w = __builtin_amdgcn_readfirstlane(threadIdx.x >> 6);
  int l = threadIdx.x & 63;
  int head = l >> 4;
  int n = blockIdx.x * 4 + w;
  int beg = rowptr[n], end = rowptr[n + 1];
  float dh = d_arr[n * HH + head];  // wave-uniform row, per-lane head select
  float a0 = 0.f, a1 = 0.f, a2 = 0.f, a3 = 0.f, den = 0.f;

  int i = beg;
  for (; i + 4 <= end; i += 4) {
    int s0 = csr_src[i], s1 = csr_src[i + 1], s2 = csr_src[i + 2], s3 = csr_src[i + 3];
    float e0 = s_arr[s0 * HH + head] + dh;
    float e1 = s_arr[s1 * HH + head] + dh;
    float e2 = s_arr[s2 * HH + head] + dh;
    float e3 = s_arr[s3 * HH + head] + dh;
    ushort4s h0 = *(const ushort4s*)(hb + (unsigned)(s0 * FDIM + l * 4));
    ushort4s h1 = *(const ushort4s*)(hb + (unsigned)(s1 * FDIM + l * 4));
    ushort4s h2 = *(const ushort4s*)(hb + (unsigned)(s2 * FDIM + l * 4));
    ushort4s h3 = *(const ushort4s*)(hb + (unsigned)(s3 * FDIM + l * 4));
    e0 = (e0 > 0.f) ? e0 : 0.2f * e0;  float w0 = __expf(e0);
    e1 = (e1 > 0.f) ? e1 : 0.2f * e1;  float w1 = __expf(e1);
    e2 = (e2 > 0.f) ? e2 : 0.2f * e2;  float w2 = __expf(e2);
    e3 = (e3 > 0.f) ? e3 : 0.2f * e3;  float w3 = __expf(e3);
    den += (w0 + w1) + (w2 + w3);
    a0 = fmaf(w0, bf2f(h0.x), a0); a1 = fmaf(w0, bf2f(h0.y), a1);
    a2 = fmaf(w0, bf2f(h0.z), a2); a3 = fmaf(w0, bf2f(h0.w), a3);
    a0 = fmaf(w1, bf2f(h1.x), a0); a1 = fmaf(w1, bf2f(h1.y), a1);
    a2 = fmaf(w1, bf2f(h1.z), a2); a3 = fmaf(w1, bf2f(h1.w), a3);
    a0 = fmaf(w2, bf2f(h2.x), a0); a1 = fmaf(w2, bf2f(h2.y), a1);
    a2 = fmaf(w2, bf2f(h2.z), a2); a3 = fmaf(w2, bf2f(h2.w), a3);
    a0 = fmaf(w3, bf2f(h3.x), a0); a1 = fmaf(w3, bf2f(h3.y), a1);
    a2 = fmaf(w3, bf2f(h3.z), a2); a3 = fmaf(w3, bf2f(h3.w), a3);
  }
  for (; i < end; i++) {
    int s0 = csr_src[i];
    float e0 = s_arr[s0 * HH + head] + dh;
    ushort4s h0 = *(const ushort4s*)(hb + (unsigned)(s0 * FDIM + l * 4));
    e0 = (e0 > 0.f) ? e0 : 0.2f * e0;
    float w0 = __expf(e0);
    den += w0;
    a0 = fmaf(w0, bf2f(h0.x), a0); a1 = fmaf(w0, bf2f(h0.y), a1);
    a2 = fmaf(w0, bf2f(h0.z), a2); a3 = fmaf(w0, bf2f(h0.w), a3);
  }
  float inv = 1.0f / den;  // self loop guarantees den > 0
  float r0 = a0 * inv, r1 = a1 * inv, r2 = a2 * inv, r3 = a3 * inv;

  if (CONCAT) {
    float4 bv = ((const float4*)bias)[l];
    ushort4s o;
    o.x = f2bf(r0 + bv.x); o.y = f2bf(r1 + bv.y);
    o.z = f2bf(r2 + bv.z); o.w = f2bf(r3 + bv.w);
    ((ushort4s*)outp)[(unsigned)(n * 64 + l)] = o;
  } else {
    // mean over heads: sum lanes {m, m+16, m+32, m+48}
    r0 += __shfl_xor(r0, 16); r1 += __shfl_xor(r1, 16);
    r2 += __shfl_xor(r2, 16); r3 += __shfl_xor(r3, 16);
    r0 += __shfl_xor(r0, 32); r1 += __shfl_xor(r1, 32);
    r2 += __shfl_xor(r2, 32); r3 += __shfl_xor(r3, 32);
    if (l < 16) {
      float4 bv = ((const float4*)bias)[l];
      float4 o;
      o.x = 0.25f * r0 + bv.x; o.y = 0.25f * r1 + bv.y;
      o.z = 0.25f * r2 + bv.z; o.w = 0.25f * r3 + bv.w;
      ((float4*)outp)[(unsigned)(n * 16 + l)] = o;
    }
  }
}

// ---------- GraphNorm ----------
__global__ __launch_bounds__(256) void norm_reduce_bf(const ushort* __restrict__ xin,
                                                      float* colsum, float* colsumsq) {
  int f = threadIdx.x;
  int r0 = blockIdx.x * 128;
  int r1 = min(NN, r0 + 128);
  float s1 = 0.f, s2 = 0.f;
  for (int r = r0; r < r1; r++) {
    float v = bf2f(xin[(size_t)r * FDIM + f]);
    s1 += v; s2 += v * v;
  }
  atomicAdd(&colsum[f], s1);
  atomicAdd(&colsumsq[f], s2);
}

__global__ __launch_bounds__(256) void norm_reduce_f32(const float* __restrict__ xin,
                                                       float* colsum, float* colsumsq) {
  int f = threadIdx.x & (CC - 1);
  int rl = threadIdx.x / CC;
  int r0 = blockIdx.x * 128;
  int r1 = min(NN, r0 + 128);
  float s1 = 0.f, s2 = 0.f;
  for (int r = r0 + rl; r < r1; r += 4) {
    float v = xin[(size_t)r * CC + f];
    s1 += v; s2 += v * v;
  }
  atomicAdd(&colsum[f], s1);
  atomicAdd(&colsumsq[f], s2);
}

// finalize folded in: each block recomputes scale/shift, then grid-stride apply
__global__ __launch_bounds__(256) void norm_apply_bf(const ushort* __restrict__ in,
                                                     ushort* __restrict__ outb,
                                                     const float* __restrict__ colsum,
                                                     const float* __restrict__ colsumsq,
                                                     const float* __restrict__ ga,
                                                     const float* __restrict__ gw,
                                                     const float* __restrict__ gb) {
  __shared__ float sc[FDIM], sh[FDIM];
  int t = threadIdx.x;
  {
    const float invn = 1.0f / (float)NN;
    float mu = colsum[t] * invn;
    float ex2 = colsumsq[t] * invn;
    float a = ga[t];
    float var = fmaxf(ex2 - (2.f * a - a * a) * mu * mu, 0.f);
    float s = gw[t] * rsqrtf(var + 1e-5f);
    sc[t] = s; sh[t] = gb[t] - s * a * mu;
  }
  __syncthreads();
  const int total = NN * FDIM / 4;
  for (int i = blockIdx.x * 256 + t; i < total; i += gridDim.x * 256) {
    int f0 = (i * 4) & (FDIM - 1);
    ushort4s v = ((const ushort4s*)in)[i];
    float y0 = sc[f0 + 0] * bf2f(v.x) + sh[f0 + 0];
    float y1 = sc[f0 + 1] * bf2f(v.y) + sh[f0 + 1];
    float y2 = sc[f0 + 2] * bf2f(v.z) + sh[f0 + 2];
    float y3 = sc[f0 + 3] * bf2f(v.w) + sh[f0 + 3];
    ushort4s o;
    o.x = f2bf((y0 > 0.f) ? y0 : 0.01f * y0);
    o.y = f2bf((y1 > 0.f) ? y1 : 0.01f * y1);
    o.z = f2bf((y2 > 0.f) ? y2 : 0.01f * y2);
    o.w = f2bf((y3 > 0.f) ? y3 : 0.01f * y3);
    ((ushort4s*)outb)[i] = o;
  }
}

// ---------- MLP 64->32->16->2 with fused GraphNorm+LeakyReLU on input ----------
__global__ __launch_bounds__(256) void mlp_kernel(const float* __restrict__ xin,
                                                  const float* __restrict__ colsum,
                                                  const float* __restrict__ colsumsq,
                                                  const float* __restrict__ ga,
                                                  const float* __restrict__ gw,
                                                  const float* __restrict__ gb,
                                                  const float* mW0, const float* mb0,
                                                  const float* mW1, const float* mb1,
                                                  const float* mW2, const float* mb2,
                                                  float* __restrict__ out) {
  __shared__ float W0s[64 * 32];
  __shared__ float W1s[32 * 16];
  __shared__ float W2s[16 * 2];
  __shared__ float b0s[32], b1s[16], b2s[2];
  __shared__ float sc[CC], sh[CC];
  int t = threadIdx.x;
  for (int i = t; i < 2048; i += 256) W0s[i] = mW0[i];
  for (int i = t; i < 512; i += 256) W1s[i] = mW1[i];
  if (t < 32) { W2s[t] = mW2[t]; b0s[t] = mb0[t]; }
  if (t < 16) b1s[t] = mb1[t];
  if (t < 2) b2s[t] = mb2[t];
  if (t < CC) {
    const float invn = 1.0f / (float)NN;
    float mu = colsum[t] * invn;
    float ex2 = colsumsq[t] * invn;
    float a = ga[t];
    float var = fmaxf(ex2 - (2.f * a - a * a) * mu * mu, 0.f);
    float s = gw[t] * rsqrtf(var + 1e-5f);
    sc[t] = s; sh[t] = gb[t] - s * a * mu;
  }
  __syncthreads();
  int node = blockIdx.x * 256 + t;
  if (node >= NN) return;
  float in[64];
  const float* xr = xin + (size_t)node * 64;
#pragma unroll
  for (int k = 0; k < 64; k++) {
    float y = sc[k] * xr[k] + sh[k];
    in[k] = (y > 0.f) ? y : 0.01f * y;   // GraphNorm + LeakyReLU(0.01) fused
  }
  float h1[32];
#pragma unroll
  for (int j = 0; j < 32; j++) h1[j] = b0s[j];
#pragma unroll
  for (int k = 0; k < 64; k++) {
    float v = in[k];
#pragma unroll
    for (int j = 0; j < 32; j++) h1[j] += v * W0s[k * 32 + j];
  }
#pragma unroll
  for (int j = 0; j < 32; j++) h1[j] = fmaxf(h1[j], 0.f);
  float h2[16];
#pragma unroll
  for (int j = 0; j < 16; j++) h2[j] = b1s[j];
#pragma unroll
  for (int k = 0; k < 32; k++) {
    float v = h1[k];
#pragma unroll
    for (int j = 0; j < 16; j++) h2[j] += v * W1s[k * 16 + j];
  }
#pragma unroll
  for (int j = 0; j < 16; j++) h2[j] = fmaxf(h2[j], 0.f);
  float o0 = b2s[0], o1 = b2s[1];
#pragma unroll
  for (int k = 0; k < 16; k++) {
    o0 += h2[k] * W2s[k * 2 + 0];
    o1 += h2[k] * W2s[k * 2 + 1];
  }
  out[(size_t)node * 2 + 0] = o0;
  out[(size_t)node * 2 + 1] = o1;
}

extern "C" void kernel_launch(void* const* d_in, const int* in_sizes, int n_in,
                              void* d_out, int out_size, void* d_ws, size_t ws_size,
                              hipStream_t stream) {
  const float* x = (const float*)d_in[0];
  const void* ei = d_in[1];
  const float* W[3]   = {(const float*)d_in[2],  (const float*)d_in[9],  (const float*)d_in[16]};
  const float* as_[3] = {(const float*)d_in[3],  (const float*)d_in[10], (const float*)d_in[17]};
  const float* ad_[3] = {(const float*)d_in[4],  (const float*)d_in[11], (const float*)d_in[18]};
  const float* b_[3]  = {(const float*)d_in[5],  (const float*)d_in[12], (const float*)d_in[19]};
  const float* gw[3]  = {(const float*)d_in[6],  (const float*)d_in[13], (const float*)d_in[20]};
  const float* gb[3]  = {(const float*)d_in[7],  (const float*)d_in[14], (const float*)d_in[21]};
  const float* ga[3]  = {(const float*)d_in[8],  (const float*)d_in[15], (const float*)d_in[22]};
  const float* mW0 = (const float*)d_in[23];
  const float* mb0 = (const float*)d_in[24];
  const float* mW1 = (const float*)d_in[25];
  const float* mb1 = (const float*)d_in[26];
  const float* mW2 = (const float*)d_in[27];
  const float* mb2 = (const float*)d_in[28];
  float* out = (float*)d_out;

  char* ws = (char*)d_ws;
  size_t off = 0;
  auto take = [&](size_t bytes) -> char* {
    char* p = ws + off;
    off = (off + bytes + 255) & ~(size_t)255;
    return p;
  };
  ushort* xb    = (ushort*)take((size_t)NN * FDIM * 2);
  ushort* hb    = (ushort*)take((size_t)NN * FDIM * 2);
  ushort* yb    = (ushort*)take((size_t)NN * FDIM * 2);
  ushort* aggb  = (ushort*)take((size_t)NN * FDIM * 2);
  float* bufD   = (float*)take((size_t)NN * CC * 4);
  ushort* Wt[3];
  for (int i = 0; i < 3; i++) Wt[i] = (ushort*)take((size_t)256 * 256 * 2);
  // s_arr | d_arr | colsum | colsumsq contiguous -> single memset per layer
  float* s_arr  = (float*)take((size_t)NN * HH * 4);   // 800000 B (multiple of 256)
  float* d_arr  = (float*)take((size_t)NN * HH * 4);
  float* colsum   = (float*)take(1024);
  float* colsumsq = (float*)take(1024);
  const size_t zero_bytes = (size_t)NN * HH * 4 * 2 + 2048;
  int* deg      = (int*)take((size_t)NN * 4);
  int* cursor   = (int*)take((size_t)NN * 4);
  int* rowptr   = (int*)take((size_t)(NN + 1) * 4);
  int* csr_src  = (int*)take((size_t)ET * 4);
  int* bsum     = (int*)take(512);
  int* boff     = (int*)take(512);
  int* flag     = (int*)take(256);

  // CSR build (reused by all 3 layers)
  hipMemsetAsync(deg, 0, (size_t)NN * 4, stream);
  detect_kernel<<<1, 256, 0, stream>>>((const unsigned int*)ei, flag);
  degree_kernel<<<(ET + 255) / 256, 256, 0, stream>>>(ei, flag, deg);
  scan1_kernel<<<SCAN_NB, SCAN_BLK, 0, stream>>>(deg, rowptr, bsum);
  scan2_kernel<<<1, 128, 0, stream>>>(bsum, boff, rowptr);
  scan3_kernel<<<SCAN_NB, SCAN_BLK, 0, stream>>>(rowptr, cursor, boff);
  fill_kernel<<<(ET + 255) / 256, 256, 0, stream>>>(ei, flag, cursor, csr_src);

  // dtype prep
  conv_x_kernel<<<(NN * FDIM / 4 + 255) / 256, 256, 0, stream>>>(x, xb);
  conv_w_kernel<<<dim3(256, 3), 256, 0, stream>>>(W[0], W[1], W[2], Wt[0], Wt[1], Wt[2]);

  const ushort* lin = xb;
  for (int L = 0; L < 3; L++) {
    hipMemsetAsync(s_arr, 0, zero_bytes, stream);  // s,d accumulators + colsum(sq)
    gemm_bf16<<<dim3((NN + 127) / 128, 2), 256, 0, stream>>>(lin, Wt[L], hb,
                                                             as_[L], ad_[L], s_arr, d_arr);
    if (L < 2) {
      agg_kernel<true><<<NN / 4, 256, 0, stream>>>(hb, s_arr, d_arr, rowptr, csr_src, b_[L], aggb);
      norm_reduce_bf<<<(NN + 127) / 128, 256, 0, stream>>>(aggb, colsum, colsumsq);
      norm_apply_bf<<<1024, 256, 0, stream>>>(aggb, yb, colsum, colsumsq, ga[L], gw[L], gb[L]);
      lin = yb;
    } else {
      agg_kernel<false><<<NN / 4, 256, 0, stream>>>(hb, s_arr, d_arr, rowptr, csr_src, b_[L], bufD);
      norm_reduce_f32<<<(NN + 127) / 128, 256, 0, stream>>>(bufD, colsum, colsumsq);
    }
  }
  mlp_kernel<<<(NN + 255) / 256, 256, 0, stream>>>(bufD, colsum, colsumsq,
                                                   ga[2], gw[2], gb[2],
                                                   mW0, mb0, mW1, mb1, mW2, mb2, out);
}

// Round 7
// 726.649 us; speedup vs baseline: 1.0095x; 1.0095x over previous
//
#include <hip/hip_runtime.h>

#define NN 50000
#define EE 800000
#define ET 850000   // EE + NN self loops
#define HH 4
#define CC 64
#define FDIM 256    // HH*CC

#define SCAN_BLK 512
#define SCAN_NB ((NN + SCAN_BLK - 1) / SCAN_BLK)   // 98

typedef unsigned short ushort;
typedef __bf16 bf16x8 __attribute__((ext_vector_type(8)));
typedef float floatx4 __attribute__((ext_vector_type(4)));
typedef ushort ushort8v __attribute__((ext_vector_type(8)));
struct ushort4s { ushort x, y, z, w; };

#define GLOBAL_AS __attribute__((address_space(1)))
#define LDS_AS __attribute__((address_space(3)))

__device__ __forceinline__ ushort f2bf(float f) {
  union { float f; unsigned u; } v; v.f = f;
  unsigned r = v.u + 0x7fffu + ((v.u >> 16) & 1u);  // RNE
  return (ushort)(r >> 16);
}
__device__ __forceinline__ float bf2f(ushort u) {
  return __uint_as_float(((unsigned)u) << 16);
}

// ---------- edge-index dtype handling (int32 vs int64 at runtime) ----------
__device__ __forceinline__ int get_edge(const void* p, int is64, long long idx) {
  if (is64) return (int)((const long long*)p)[idx];
  return ((const int*)p)[idx];
}

__global__ void detect_kernel(const unsigned int* p, int* flag) {
  // int64 with values < 50000 => every odd 32-bit word is 0
  __shared__ unsigned red[256];
  int t = threadIdx.x;
  unsigned o = 0;
  for (int i = 0; i < 4; i++) o |= p[(t * 4 + i) * 2 + 1];
  red[t] = o;
  __syncthreads();
  for (int s = 128; s > 0; s >>= 1) {
    if (t < s) red[t] |= red[t + s];
    __syncthreads();
  }
  if (t == 0) *flag = (red[0] == 0) ? 1 : 0;
}

// ---------- CSR build over dst ----------
__global__ void degree_kernel(const void* eidx, const int* flag, int* deg) {
  int k = blockIdx.x * blockDim.x + threadIdx.x;
  if (k >= ET) return;
  int is64 = *flag;
  int dst = (k < EE) ? get_edge(eidx, is64, (long long)EE + k) : (k - EE);
  atomicAdd(&deg[dst], 1);
}

__global__ __launch_bounds__(SCAN_BLK) void scan1_kernel(const int* __restrict__ deg,
                                                         int* __restrict__ rowptr,
                                                         int* __restrict__ bsum) {
  __shared__ int sm[SCAN_BLK];
  int t = threadIdx.x;
  int i = blockIdx.x * SCAN_BLK + t;
  int v = (i < NN) ? deg[i] : 0;
  sm[t] = v;
  __syncthreads();
#pragma unroll
  for (int o = 1; o < SCAN_BLK; o <<= 1) {
    int u = (t >= o) ? sm[t - o] : 0;
    __syncthreads();
    sm[t] += u;
    __syncthreads();
  }
  if (i < NN) rowptr[i] = sm[t] - v;                 // local exclusive
  if (t == SCAN_BLK - 1) bsum[blockIdx.x] = sm[t];   // block total
}

__global__ __launch_bounds__(128) void scan2_kernel(const int* __restrict__ bsum,
                                                    int* __restrict__ boff,
                                                    int* __restrict__ rowptr) {
  __shared__ int sm[128];
  int t = threadIdx.x;
  int v = (t < SCAN_NB) ? bsum[t] : 0;
  sm[t] = v;
  __syncthreads();
#pragma unroll
  for (int o = 1; o < 128; o <<= 1) {
    int u = (t >= o) ? sm[t - o] : 0;
    __syncthreads();
    sm[t] += u;
    __syncthreads();
  }
  if (t < SCAN_NB) boff[t] = sm[t] - v;  // exclusive block offset
  if (t == 0) rowptr[NN] = ET;
}

__global__ __launch_bounds__(SCAN_BLK) void scan3_kernel(int* __restrict__ rowptr,
                                                         int* __restrict__ cursor,
                                                         const int* __restrict__ boff) {
  int i = blockIdx.x * SCAN_BLK + threadIdx.x;
  if (i >= NN) return;
  int v = rowptr[i] + boff[blockIdx.x];
  rowptr[i] = v;
  cursor[i] = v;
}

__global__ void fill_kernel(const void* eidx, const int* flag, int* cursor, int* csr_src) {
  int k = blockIdx.x * blockDim.x + threadIdx.x;
  if (k >= ET) return;
  int is64 = *flag;
  int src, dst;
  if (k < EE) {
    src = get_edge(eidx, is64, k);
    dst = get_edge(eidx, is64, (long long)EE + k);
  } else {
    src = dst = k - EE;
  }
  int pos = atomicAdd(&cursor[dst], 1);
  csr_src[pos] = src;
}

// ---------- dtype conversions ----------
__global__ void conv_x_kernel(const float* __restrict__ x, ushort* __restrict__ xb) {
  int i = blockIdx.x * 256 + threadIdx.x;
  float4 v = ((const float4*)x)[i];
  ushort4s o;
  o.x = f2bf(v.x); o.y = f2bf(v.y); o.z = f2bf(v.z); o.w = f2bf(v.w);
  ((ushort4s*)xb)[i] = o;
}

// all three weight transposes in one dispatch (grid.y selects the matrix)
__global__ void conv_w_kernel(const float* __restrict__ W0, const float* __restrict__ W1,
                              const float* __restrict__ W2,
                              ushort* __restrict__ T0, ushort* __restrict__ T1,
                              ushort* __restrict__ T2) {
  const float* W = (blockIdx.y == 0) ? W0 : (blockIdx.y == 1) ? W1 : W2;
  ushort* Wt = (blockIdx.y == 0) ? T0 : (blockIdx.y == 1) ? T1 : T2;
  int idx = blockIdx.x * 256 + threadIdx.x;  // 65536
  int k = idx >> 8, n = idx & 255;
  Wt[n * 256 + k] = f2bf(W[idx]);  // transpose: Wt[n][k]
}

// ---------- bf16 MFMA GEMM: C[M,256] = A[M,256] @ B[256,256], B given transposed ----------
// Staging via global_load_lds width=16: dest = wave-uniform base (sub-tile s*512
// ushorts) + lane*16B, which is exactly our fragment-order layout.
__global__ __launch_bounds__(256) void gemm_bf16(const ushort* __restrict__ A,
                                                 const ushort* __restrict__ Bt,
                                                 ushort* __restrict__ C) {
  __shared__ ushort As[8 * 512];
  __shared__ ushort Bs[8 * 512];
  int tid = threadIdx.x, w = tid >> 6, l = tid & 63;
  int brow0 = blockIdx.x * 128, bcol0 = blockIdx.y * 128;
  int lm = l & 15, lk = (l >> 4) * 8;
  int s0 = 2 * w, s1 = 2 * w + 1;
  int ar0 = min(brow0 + s0 * 16 + lm, NN - 1);
  int ar1 = min(brow0 + s1 * 16 + lm, NN - 1);
  const ushort* ag0 = A + (size_t)ar0 * 256 + lk;
  const ushort* ag1 = A + (size_t)ar1 * 256 + lk;
  const ushort* bg0 = Bt + (size_t)(bcol0 + s0 * 16 + lm) * 256 + lk;
  const ushort* bg1 = Bt + (size_t)(bcol0 + s1 * 16 + lm) * 256 + lk;

  floatx4 acc[4][4];
#pragma unroll
  for (int i = 0; i < 4; i++)
#pragma unroll
    for (int j = 0; j < 4; j++) acc[i][j] = floatx4{0.f, 0.f, 0.f, 0.f};

  int wm = (w >> 1) * 4, wn = (w & 1) * 4;

  for (int k0 = 0; k0 < 256; k0 += 32) {
    __builtin_amdgcn_global_load_lds((const GLOBAL_AS void*)(ag0 + k0),
                                     (LDS_AS void*)&As[s0 * 512], 16, 0, 0);
    __builtin_amdgcn_global_load_lds((const GLOBAL_AS void*)(ag1 + k0),
                                     (LDS_AS void*)&As[s1 * 512], 16, 0, 0);
    __builtin_amdgcn_global_load_lds((const GLOBAL_AS void*)(bg0 + k0),
                                     (LDS_AS void*)&Bs[s0 * 512], 16, 0, 0);
    __builtin_amdgcn_global_load_lds((const GLOBAL_AS void*)(bg1 + k0),
                                     (LDS_AS void*)&Bs[s1 * 512], 16, 0, 0);
    __syncthreads();
    bf16x8 af[4], bfr[4];
#pragma unroll
    for (int i = 0; i < 4; i++) af[i] = *(const bf16x8*)&As[(wm + i) * 512 + l * 8];
#pragma unroll
    for (int j = 0; j < 4; j++) bfr[j] = *(const bf16x8*)&Bs[(wn + j) * 512 + l * 8];
#pragma unroll
    for (int i = 0; i < 4; i++)
#pragma unroll
      for (int j = 0; j < 4; j++)
        acc[i][j] = __builtin_amdgcn_mfma_f32_16x16x32_bf16(af[i], bfr[j], acc[i][j], 0, 0, 0);
    __syncthreads();
  }

  int quad = l >> 4;
#pragma unroll
  for (int i = 0; i < 4; i++) {
    int r0 = brow0 + (wm + i) * 16 + quad * 4;
#pragma unroll
    for (int j = 0; j < 4; j++) {
      int col = bcol0 + (wn + j) * 16 + lm;
#pragma unroll
      for (int r = 0; r < 4; r++) {
        int row = r0 + r;
        if (row < NN) C[(size_t)row * 256 + col] = f2bf(acc[i][j][r]);
      }
    }
  }
}

// ---------- attention logits s,d: one wave per node, lane l = channels [4l,4l+4) ----------
__global__ __launch_bounds__(256) void sd_kernel(const ushort* __restrict__ h,
                                                 const float* __restrict__ as_,
                                                 const float* __restrict__ ad_,
                                                 float* __restrict__ s, float* __restrict__ d) {
  int w = threadIdx.x >> 6;
  int l = threadIdx.x & 63;
  int n = blockIdx.x * 4 + w;
  ushort4s hv = *(const ushort4s*)(h + (size_t)n * FDIM + l * 4);
  float4 av = ((const float4*)as_)[l];
  float4 dv = ((const float4*)ad_)[l];
  float f0 = bf2f(hv.x), f1 = bf2f(hv.y), f2 = bf2f(hv.z), f3 = bf2f(hv.w);
  float ps = f0 * av.x + f1 * av.y + f2 * av.z + f3 * av.w;
  float pd = f0 * dv.x + f1 * dv.y + f2 * dv.z + f3 * dv.w;
#pragma unroll
  for (int o = 1; o < 16; o <<= 1) {
    ps += __shfl_xor(ps, o);
    pd += __shfl_xor(pd, o);
  }
  if ((l & 15) == 0) {
    s[n * HH + (l >> 4)] = ps;
    d[n * HH + (l >> 4)] = pd;
  }
}

// ---------- aggregation: one wave per node, all heads; fused edge softmax ----------
template <bool CONCAT>
__global__ __launch_bounds__(256) void agg_kernel(const ushort* __restrict__ hb,
                                                  const float* __restrict__ s_arr,
                                                  const float* __restrict__ d_arr,
                                                  const int* __restrict__ rowptr,
                                                  const int* __restrict__ csr_src,
                                                  const float* __restrict__ bias,
                                                  void* __restrict__ outp) {
  int w = __builtin_amdgcn_readfirstlane(threadIdx.x >> 6);
  int l = threadIdx.x & 63;
  int head = l >> 4;
  int n = blockIdx.x * 4 + w;
  int beg = rowptr[n], end = rowptr[n + 1];
  float dh = d_arr[n * HH + head];  // wave-uniform row, per-lane head select
  float a0 = 0.f, a1 = 0.f, a2 = 0.f, a3 = 0.f, den = 0.f;

  int i = beg;
  for (; i + 4 <= end; i += 4) {
    int s0 = csr_src[i], s1 = csr_src[i + 1], s2 = csr_src[i + 2], s3 = csr_src[i + 3];
    float e0 = s_arr[s0 * HH + head] + dh;
    float e1 = s_arr[s1 * HH + head] + dh;
    float e2 = s_arr[s2 * HH + head] + dh;
    float e3 = s_arr[s3 * HH + head] + dh;
    ushort4s h0 = *(const ushort4s*)(hb + (unsigned)(s0 * FDIM + l * 4));
    ushort4s h1 = *(const ushort4s*)(hb + (unsigned)(s1 * FDIM + l * 4));
    ushort4s h2 = *(const ushort4s*)(hb + (unsigned)(s2 * FDIM + l * 4));
    ushort4s h3 = *(const ushort4s*)(hb + (unsigned)(s3 * FDIM + l * 4));
    e0 = (e0 > 0.f) ? e0 : 0.2f * e0;  float w0 = __expf(e0);
    e1 = (e1 > 0.f) ? e1 : 0.2f * e1;  float w1 = __expf(e1);
    e2 = (e2 > 0.f) ? e2 : 0.2f * e2;  float w2 = __expf(e2);
    e3 = (e3 > 0.f) ? e3 : 0.2f * e3;  float w3 = __expf(e3);
    den += (w0 + w1) + (w2 + w3);
    a0 = fmaf(w0, bf2f(h0.x), a0); a1 = fmaf(w0, bf2f(h0.y), a1);
    a2 = fmaf(w0, bf2f(h0.z), a2); a3 = fmaf(w0, bf2f(h0.w), a3);
    a0 = fmaf(w1, bf2f(h1.x), a0); a1 = fmaf(w1, bf2f(h1.y), a1);
    a2 = fmaf(w1, bf2f(h1.z), a2); a3 = fmaf(w1, bf2f(h1.w), a3);
    a0 = fmaf(w2, bf2f(h2.x), a0); a1 = fmaf(w2, bf2f(h2.y), a1);
    a2 = fmaf(w2, bf2f(h2.z), a2); a3 = fmaf(w2, bf2f(h2.w), a3);
    a0 = fmaf(w3, bf2f(h3.x), a0); a1 = fmaf(w3, bf2f(h3.y), a1);
    a2 = fmaf(w3, bf2f(h3.z), a2); a3 = fmaf(w3, bf2f(h3.w), a3);
  }
  for (; i < end; i++) {
    int s0 = csr_src[i];
    float e0 = s_arr[s0 * HH + head] + dh;
    ushort4s h0 = *(const ushort4s*)(hb + (unsigned)(s0 * FDIM + l * 4));
    e0 = (e0 > 0.f) ? e0 : 0.2f * e0;
    float w0 = __expf(e0);
    den += w0;
    a0 = fmaf(w0, bf2f(h0.x), a0); a1 = fmaf(w0, bf2f(h0.y), a1);
    a2 = fmaf(w0, bf2f(h0.z), a2); a3 = fmaf(w0, bf2f(h0.w), a3);
  }
  float inv = 1.0f / den;  // self loop guarantees den > 0
  float r0 = a0 * inv, r1 = a1 * inv, r2 = a2 * inv, r3 = a3 * inv;

  if (CONCAT) {
    float4 bv = ((const float4*)bias)[l];
    ushort4s o;
    o.x = f2bf(r0 + bv.x); o.y = f2bf(r1 + bv.y);
    o.z = f2bf(r2 + bv.z); o.w = f2bf(r3 + bv.w);
    ((ushort4s*)outp)[(unsigned)(n * 64 + l)] = o;
  } else {
    // mean over heads: sum lanes {m, m+16, m+32, m+48}
    r0 += __shfl_xor(r0, 16); r1 += __shfl_xor(r1, 16);
    r2 += __shfl_xor(r2, 16); r3 += __shfl_xor(r3, 16);
    r0 += __shfl_xor(r0, 32); r1 += __shfl_xor(r1, 32);
    r2 += __shfl_xor(r2, 32); r3 += __shfl_xor(r3, 32);
    if (l < 16) {
      float4 bv = ((const float4*)bias)[l];
      float4 o;
      o.x = 0.25f * r0 + bv.x; o.y = 0.25f * r1 + bv.y;
      o.z = 0.25f * r2 + bv.z; o.w = 0.25f * r3 + bv.w;
      ((float4*)outp)[(unsigned)(n * 16 + l)] = o;
    }
  }
}

// ---------- GraphNorm ----------
// ushort4 loads (512B/wave/inst), LDS pre-reduction, 512 atomics per block
__global__ __launch_bounds__(256) void norm_reduce_bf(const ushort* __restrict__ xin,
                                                      float* colsum, float* colsumsq) {
  __shared__ float4 sm1[256], sm2[256];
  int t = threadIdx.x;
  int c4 = (t & 63) * 4;
  int rl = t >> 6;
  int r0 = blockIdx.x * 128;
  int r1 = min(NN, r0 + 128);
  float s0 = 0.f, s1 = 0.f, s2 = 0.f, s3 = 0.f;
  float q0 = 0.f, q1 = 0.f, q2 = 0.f, q3 = 0.f;
  for (int r = r0 + rl; r < r1; r += 4) {
    ushort4s v = *(const ushort4s*)(xin + (size_t)r * FDIM + c4);
    float f0 = bf2f(v.x), f1 = bf2f(v.y), f2 = bf2f(v.z), f3 = bf2f(v.w);
    s0 += f0; q0 += f0 * f0;
    s1 += f1; q1 += f1 * f1;
    s2 += f2; q2 += f2 * f2;
    s3 += f3; q3 += f3 * f3;
  }
  sm1[t] = float4{s0, s1, s2, s3};
  sm2[t] = float4{q0, q1, q2, q3};
  __syncthreads();
  if (t < 64) {
    float4 a = sm1[t], b = sm1[t + 64], c = sm1[t + 128], d = sm1[t + 192];
    atomicAdd(&colsum[c4 + 0], a.x + b.x + c.x + d.x);
    atomicAdd(&colsum[c4 + 1], a.y + b.y + c.y + d.y);
    atomicAdd(&colsum[c4 + 2], a.z + b.z + c.z + d.z);
    atomicAdd(&colsum[c4 + 3], a.w + b.w + c.w + d.w);
    float4 e = sm2[t], f = sm2[t + 64], g = sm2[t + 128], h = sm2[t + 192];
    atomicAdd(&colsumsq[c4 + 0], e.x + f.x + g.x + h.x);
    atomicAdd(&colsumsq[c4 + 1], e.y + f.y + g.y + h.y);
    atomicAdd(&colsumsq[c4 + 2], e.z + f.z + g.z + h.z);
    atomicAdd(&colsumsq[c4 + 3], e.w + f.w + g.w + h.w);
  }
}

__global__ __launch_bounds__(256) void norm_reduce_f32(const float* __restrict__ xin,
                                                       float* colsum, float* colsumsq) {
  int f = threadIdx.x & (CC - 1);
  int rl = threadIdx.x / CC;
  int r0 = blockIdx.x * 128;
  int r1 = min(NN, r0 + 128);
  float s1 = 0.f, s2 = 0.f;
  for (int r = r0 + rl; r < r1; r += 4) {
    float v = xin[(size_t)r * CC + f];
    s1 += v; s2 += v * v;
  }
  atomicAdd(&colsum[f], s1);
  atomicAdd(&colsumsq[f], s2);
}

// finalize folded in: each block recomputes scale/shift, then grid-stride apply
__global__ __launch_bounds__(256) void norm_apply_bf(const ushort* __restrict__ in,
                                                     ushort* __restrict__ outb,
                                                     const float* __restrict__ colsum,
                                                     const float* __restrict__ colsumsq,
                                                     const float* __restrict__ ga,
                                                     const float* __restrict__ gw,
                                                     const float* __restrict__ gb) {
  __shared__ float sc[FDIM], sh[FDIM];
  int t = threadIdx.x;
  {
    const float invn = 1.0f / (float)NN;
    float mu = colsum[t] * invn;
    float ex2 = colsumsq[t] * invn;
    float a = ga[t];
    float var = fmaxf(ex2 - (2.f * a - a * a) * mu * mu, 0.f);
    float s = gw[t] * rsqrtf(var + 1e-5f);
    sc[t] = s; sh[t] = gb[t] - s * a * mu;
  }
  __syncthreads();
  const int total = NN * FDIM / 4;
  for (int i = blockIdx.x * 256 + t; i < total; i += gridDim.x * 256) {
    int f0 = (i * 4) & (FDIM - 1);
    ushort4s v = ((const ushort4s*)in)[i];
    float y0 = sc[f0 + 0] * bf2f(v.x) + sh[f0 + 0];
    float y1 = sc[f0 + 1] * bf2f(v.y) + sh[f0 + 1];
    float y2 = sc[f0 + 2] * bf2f(v.z) + sh[f0 + 2];
    float y3 = sc[f0 + 3] * bf2f(v.w) + sh[f0 + 3];
    ushort4s o;
    o.x = f2bf((y0 > 0.f) ? y0 : 0.01f * y0);
    o.y = f2bf((y1 > 0.f) ? y1 : 0.01f * y1);
    o.z = f2bf((y2 > 0.f) ? y2 : 0.01f * y2);
    o.w = f2bf((y3 > 0.f) ? y3 : 0.01f * y3);
    ((ushort4s*)outb)[i] = o;
  }
}

// ---------- MLP 64->32->16->2 with fused GraphNorm+LeakyReLU on input ----------
__global__ __launch_bounds__(256) void mlp_kernel(const float* __restrict__ xin,
                                                  const float* __restrict__ colsum,
                                                  const float* __restrict__ colsumsq,
                                                  const float* __restrict__ ga,
                                                  const float* __restrict__ gw,
                                                  const float* __restrict__ gb,
                                                  const float* mW0, const float* mb0,
                                                  const float* mW1, const float* mb1,
                                                  const float* mW2, const float* mb2,
                                                  float* __restrict__ out) {
  __shared__ float W0s[64 * 32];
  __shared__ float W1s[32 * 16];
  __shared__ float W2s[16 * 2];
  __shared__ float b0s[32], b1s[16], b2s[2];
  __shared__ float sc[CC], sh[CC];
  int t = threadIdx.x;
  for (int i = t; i < 2048; i += 256) W0s[i] = mW0[i];
  for (int i = t; i < 512; i += 256) W1s[i] = mW1[i];
  if (t < 32) { W2s[t] = mW2[t]; b0s[t] = mb0[t]; }
  if (t < 16) b1s[t] = mb1[t];
  if (t < 2) b2s[t] = mb2[t];
  if (t < CC) {
    const float invn = 1.0f / (float)NN;
    float mu = colsum[t] * invn;
    float ex2 = colsumsq[t] * invn;
    float a = ga[t];
    float var = fmaxf(ex2 - (2.f * a - a * a) * mu * mu, 0.f);
    float s = gw[t] * rsqrtf(var + 1e-5f);
    sc[t] = s; sh[t] = gb[t] - s * a * mu;
  }
  __syncthreads();
  int node = blockIdx.x * 256 + t;
  if (node >= NN) return;
  float in[64];
  const float* xr = xin + (size_t)node * 64;
#pragma unroll
  for (int k = 0; k < 64; k++) {
    float y = sc[k] * xr[k] + sh[k];
    in[k] = (y > 0.f) ? y : 0.01f * y;   // GraphNorm + LeakyReLU(0.01) fused
  }
  float h1[32];
#pragma unroll
  for (int j = 0; j < 32; j++) h1[j] = b0s[j];
#pragma unroll
  for (int k = 0; k < 64; k++) {
    float v = in[k];
#pragma unroll
    for (int j = 0; j < 32; j++) h1[j] += v * W0s[k * 32 + j];
  }
#pragma unroll
  for (int j = 0; j < 32; j++) h1[j] = fmaxf(h1[j], 0.f);
  float h2[16];
#pragma unroll
  for (int j = 0; j < 16; j++) h2[j] = b1s[j];
#pragma unroll
  for (int k = 0; k < 32; k++) {
    float v = h1[k];
#pragma unroll
    for (int j = 0; j < 16; j++) h2[j] += v * W1s[k * 16 + j];
  }
#pragma unroll
  for (int j = 0; j < 16; j++) h2[j] = fmaxf(h2[j], 0.f);
  float o0 = b2s[0], o1 = b2s[1];
#pragma unroll
  for (int k = 0; k < 16; k++) {
    o0 += h2[k] * W2s[k * 2 + 0];
    o1 += h2[k] * W2s[k * 2 + 1];
  }
  out[(size_t)node * 2 + 0] = o0;
  out[(size_t)node * 2 + 1] = o1;
}

extern "C" void kernel_launch(void* const* d_in, const int* in_sizes, int n_in,
                              void* d_out, int out_size, void* d_ws, size_t ws_size,
                              hipStream_t stream) {
  const float* x = (const float*)d_in[0];
  const void* ei = d_in[1];
  const float* W[3]   = {(const float*)d_in[2],  (const float*)d_in[9],  (const float*)d_in[16]};
  const float* as_[3] = {(const float*)d_in[3],  (const float*)d_in[10], (const float*)d_in[17]};
  const float* ad_[3] = {(const float*)d_in[4],  (const float*)d_in[11], (const float*)d_in[18]};
  const float* b_[3]  = {(const float*)d_in[5],  (const float*)d_in[12], (const float*)d_in[19]};
  const float* gw[3]  = {(const float*)d_in[6],  (const float*)d_in[13], (const float*)d_in[20]};
  const float* gb[3]  = {(const float*)d_in[7],  (const float*)d_in[14], (const float*)d_in[21]};
  const float* ga[3]  = {(const float*)d_in[8],  (const float*)d_in[15], (const float*)d_in[22]};
  const float* mW0 = (const float*)d_in[23];
  const float* mb0 = (const float*)d_in[24];
  const float* mW1 = (const float*)d_in[25];
  const float* mb1 = (const float*)d_in[26];
  const float* mW2 = (const float*)d_in[27];
  const float* mb2 = (const float*)d_in[28];
  float* out = (float*)d_out;

  char* ws = (char*)d_ws;
  size_t off = 0;
  auto take = [&](size_t bytes) -> char* {
    char* p = ws + off;
    off = (off + bytes + 255) & ~(size_t)255;
    return p;
  };
  ushort* xb    = (ushort*)take((size_t)NN * FDIM * 2);
  ushort* hb    = (ushort*)take((size_t)NN * FDIM * 2);
  ushort* yb    = (ushort*)take((size_t)NN * FDIM * 2);
  ushort* aggb  = (ushort*)take((size_t)NN * FDIM * 2);
  float* bufD   = (float*)take((size_t)NN * CC * 4);
  ushort* Wt[3];
  for (int i = 0; i < 3; i++) Wt[i] = (ushort*)take((size_t)256 * 256 * 2);
  float* s_arr  = (float*)take((size_t)NN * HH * 4);
  float* d_arr  = (float*)take((size_t)NN * HH * 4);
  float* colsum   = (float*)take(1024);   // colsum+colsumsq contiguous: one memset
  float* colsumsq = (float*)take(1024);
  int* deg      = (int*)take((size_t)NN * 4);
  int* cursor   = (int*)take((size_t)NN * 4);
  int* rowptr   = (int*)take((size_t)(NN + 1) * 4);
  int* csr_src  = (int*)take((size_t)ET * 4);
  int* bsum     = (int*)take(512);
  int* boff     = (int*)take(512);
  int* flag     = (int*)take(256);

  // CSR build (reused by all 3 layers)
  hipMemsetAsync(deg, 0, (size_t)NN * 4, stream);
  detect_kernel<<<1, 256, 0, stream>>>((const unsigned int*)ei, flag);
  degree_kernel<<<(ET + 255) / 256, 256, 0, stream>>>(ei, flag, deg);
  scan1_kernel<<<SCAN_NB, SCAN_BLK, 0, stream>>>(deg, rowptr, bsum);
  scan2_kernel<<<1, 128, 0, stream>>>(bsum, boff, rowptr);
  scan3_kernel<<<SCAN_NB, SCAN_BLK, 0, stream>>>(rowptr, cursor, boff);
  fill_kernel<<<(ET + 255) / 256, 256, 0, stream>>>(ei, flag, cursor, csr_src);

  // dtype prep
  conv_x_kernel<<<(NN * FDIM / 4 + 255) / 256, 256, 0, stream>>>(x, xb);
  conv_w_kernel<<<dim3(256, 3), 256, 0, stream>>>(W[0], W[1], W[2], Wt[0], Wt[1], Wt[2]);

  const ushort* lin = xb;
  for (int L = 0; L < 3; L++) {
    gemm_bf16<<<dim3((NN + 127) / 128, 2), 256, 0, stream>>>(lin, Wt[L], hb);
    sd_kernel<<<NN / 4, 256, 0, stream>>>(hb, as_[L], ad_[L], s_arr, d_arr);
    hipMemsetAsync(colsum, 0, 2048, stream);
    if (L < 2) {
      agg_kernel<true><<<NN / 4, 256, 0, stream>>>(hb, s_arr, d_arr, rowptr, csr_src, b_[L], aggb);
      norm_reduce_bf<<<(NN + 127) / 128, 256, 0, stream>>>(aggb, colsum, colsumsq);
      norm_apply_bf<<<1024, 256, 0, stream>>>(aggb, yb, colsum, colsumsq, ga[L], gw[L], gb[L]);
      lin = yb;
    } else {
      agg_kernel<false><<<NN / 4, 256, 0, stream>>>(hb, s_arr, d_arr, rowptr, csr_src, b_[L], bufD);
      norm_reduce_f32<<<(NN + 127) / 128, 256, 0, stream>>>(bufD, colsum, colsumsq);
    }
  }
  mlp_kernel<<<(NN + 255) / 256, 256, 0, stream>>>(bufD, colsum, colsumsq,
                                                   ga[2], gw[2], gb[2],
                                                   mW0, mb0, mW1, mb1, mW2, mb2, out);
}

// Round 8
// 710.332 us; speedup vs baseline: 1.0327x; 1.0230x over previous
//
#include <hip/hip_runtime.h>

#define NN 50000
#define EE 800000
#define ET 850000   // EE + NN self loops
#define HH 4
#define CC 64
#define FDIM 256    // HH*CC

#define SCAN_BLK 512
#define SCAN_NB ((NN + SCAN_BLK - 1) / SCAN_BLK)   // 98

typedef unsigned short ushort;
typedef __bf16 bf16x8 __attribute__((ext_vector_type(8)));
typedef float floatx4 __attribute__((ext_vector_type(4)));
typedef ushort ushort8v __attribute__((ext_vector_type(8)));
struct ushort4s { ushort x, y, z, w; };

__device__ __forceinline__ ushort f2bf(float f) {
  union { float f; unsigned u; } v; v.f = f;
  unsigned r = v.u + 0x7fffu + ((v.u >> 16) & 1u);  // RNE
  return (ushort)(r >> 16);
}
__device__ __forceinline__ float bf2f(ushort u) {
  return __uint_as_float(((unsigned)u) << 16);
}

// ---------- edge-index dtype handling (int32 vs int64 at runtime) ----------
__device__ __forceinline__ int get_edge(const void* p, int is64, long long idx) {
  if (is64) return (int)((const long long*)p)[idx];
  return ((const int*)p)[idx];
}

__global__ void detect_kernel(const unsigned int* p, int* flag) {
  // int64 with values < 50000 => every odd 32-bit word is 0
  __shared__ unsigned red[256];
  int t = threadIdx.x;
  unsigned o = 0;
  for (int i = 0; i < 4; i++) o |= p[(t * 4 + i) * 2 + 1];
  red[t] = o;
  __syncthreads();
  for (int s = 128; s > 0; s >>= 1) {
    if (t < s) red[t] |= red[t + s];
    __syncthreads();
  }
  if (t == 0) *flag = (red[0] == 0) ? 1 : 0;
}

// ---------- CSR build over dst ----------
__global__ void degree_kernel(const void* eidx, const int* flag, int* deg) {
  int k = blockIdx.x * blockDim.x + threadIdx.x;
  if (k >= ET) return;
  int is64 = *flag;
  int dst = (k < EE) ? get_edge(eidx, is64, (long long)EE + k) : (k - EE);
  atomicAdd(&deg[dst], 1);
}

__global__ __launch_bounds__(SCAN_BLK) void scan1_kernel(const int* __restrict__ deg,
                                                         int* __restrict__ rowptr,
                                                         int* __restrict__ bsum) {
  __shared__ int sm[SCAN_BLK];
  int t = threadIdx.x;
  int i = blockIdx.x * SCAN_BLK + t;
  int v = (i < NN) ? deg[i] : 0;
  sm[t] = v;
  __syncthreads();
#pragma unroll
  for (int o = 1; o < SCAN_BLK; o <<= 1) {
    int u = (t >= o) ? sm[t - o] : 0;
    __syncthreads();
    sm[t] += u;
    __syncthreads();
  }
  if (i < NN) rowptr[i] = sm[t] - v;                 // local exclusive
  if (t == SCAN_BLK - 1) bsum[blockIdx.x] = sm[t];   // block total
}

__global__ __launch_bounds__(128) void scan2_kernel(const int* __restrict__ bsum,
                                                    int* __restrict__ boff,
                                                    int* __restrict__ rowptr) {
  __shared__ int sm[128];
  int t = threadIdx.x;
  int v = (t < SCAN_NB) ? bsum[t] : 0;
  sm[t] = v;
  __syncthreads();
#pragma unroll
  for (int o = 1; o < 128; o <<= 1) {
    int u = (t >= o) ? sm[t - o] : 0;
    __syncthreads();
    sm[t] += u;
    __syncthreads();
  }
  if (t < SCAN_NB) boff[t] = sm[t] - v;  // exclusive block offset
  if (t == 0) rowptr[NN] = ET;
}

__global__ __launch_bounds__(SCAN_BLK) void scan3_kernel(int* __restrict__ rowptr,
                                                         int* __restrict__ cursor,
                                                         const int* __restrict__ boff) {
  int i = blockIdx.x * SCAN_BLK + threadIdx.x;
  if (i >= NN) return;
  int v = rowptr[i] + boff[blockIdx.x];
  rowptr[i] = v;
  cursor[i] = v;
}

__global__ void fill_kernel(const void* eidx, const int* flag, int* cursor, int* csr_src) {
  int k = blockIdx.x * blockDim.x + threadIdx.x;
  if (k >= ET) return;
  int is64 = *flag;
  int src, dst;
  if (k < EE) {
    src = get_edge(eidx, is64, k);
    dst = get_edge(eidx, is64, (long long)EE + k);
  } else {
    src = dst = k - EE;
  }
  int pos = atomicAdd(&cursor[dst], 1);
  csr_src[pos] = src;
}

// all three weight transposes in one dispatch (grid.y selects the matrix)
__global__ void conv_w_kernel(const float* __restrict__ W0, const float* __restrict__ W1,
                              const float* __restrict__ W2,
                              ushort* __restrict__ T0, ushort* __restrict__ T1,
                              ushort* __restrict__ T2) {
  const float* W = (blockIdx.y == 0) ? W0 : (blockIdx.y == 1) ? W1 : W2;
  ushort* Wt = (blockIdx.y == 0) ? T0 : (blockIdx.y == 1) ? T1 : T2;
  int idx = blockIdx.x * 256 + threadIdx.x;  // 65536
  int k = idx >> 8, n = idx & 255;
  Wt[n * 256 + k] = f2bf(W[idx]);  // transpose: Wt[n][k]
}

// ---------- bf16 MFMA GEMM + no-atomic s/d epilogue ----------
// C[M,256] = A[M,256] @ B[256,256] (B given transposed). AF32: A is f32,
// converted to bf16 inline during staging (layer 0 reads x directly).
// Epilogue: wave w of block (x,y) holds the COMPLETE head y*2+(w&1) for rows
// brow0+(w>>1)*64..+64 -> plain stores of s,d (each (row,head) written once).
template <int AF32>
__global__ __launch_bounds__(256) void gemm_bf16(const void* __restrict__ Ap,
                                                 const ushort* __restrict__ Bt,
                                                 ushort* __restrict__ C,
                                                 const float* __restrict__ as_,
                                                 const float* __restrict__ ad_,
                                                 float* __restrict__ s_arr,
                                                 float* __restrict__ d_arr) {
  __shared__ ushort As[8 * 512];
  __shared__ ushort Bs[8 * 512];
  int tid = threadIdx.x, w = tid >> 6, l = tid & 63;
  int brow0 = blockIdx.x * 128, bcol0 = blockIdx.y * 128;
  int lm = l & 15, lk = (l >> 4) * 8;
  int s0 = 2 * w, s1 = 2 * w + 1;
  int ar0 = min(brow0 + s0 * 16 + lm, NN - 1);
  int ar1 = min(brow0 + s1 * 16 + lm, NN - 1);
  size_t arow0 = (size_t)ar0 * 256 + lk;
  size_t arow1 = (size_t)ar1 * 256 + lk;
  const ushort* bg0 = Bt + (size_t)(bcol0 + s0 * 16 + lm) * 256 + lk;
  const ushort* bg1 = Bt + (size_t)(bcol0 + s1 * 16 + lm) * 256 + lk;

  floatx4 acc[4][4];
#pragma unroll
  for (int i = 0; i < 4; i++)
#pragma unroll
    for (int j = 0; j < 4; j++) acc[i][j] = floatx4{0.f, 0.f, 0.f, 0.f};

  int wm = (w >> 1) * 4, wn = (w & 1) * 4;

  for (int k0 = 0; k0 < 256; k0 += 32) {
    ushort8v a0, a1;
    if constexpr (AF32) {
      const float* p0 = (const float*)Ap + arow0 + k0;
      const float* p1 = (const float*)Ap + arow1 + k0;
      float4 u0 = *(const float4*)p0, v0 = *(const float4*)(p0 + 4);
      float4 u1 = *(const float4*)p1, v1 = *(const float4*)(p1 + 4);
      a0 = ushort8v{f2bf(u0.x), f2bf(u0.y), f2bf(u0.z), f2bf(u0.w),
                    f2bf(v0.x), f2bf(v0.y), f2bf(v0.z), f2bf(v0.w)};
      a1 = ushort8v{f2bf(u1.x), f2bf(u1.y), f2bf(u1.z), f2bf(u1.w),
                    f2bf(v1.x), f2bf(v1.y), f2bf(v1.z), f2bf(v1.w)};
    } else {
      a0 = *(const ushort8v*)((const ushort*)Ap + arow0 + k0);
      a1 = *(const ushort8v*)((const ushort*)Ap + arow1 + k0);
    }
    ushort8v b0 = *(const ushort8v*)(bg0 + k0);
    ushort8v b1 = *(const ushort8v*)(bg1 + k0);
    *(ushort8v*)&As[s0 * 512 + l * 8] = a0;
    *(ushort8v*)&As[s1 * 512 + l * 8] = a1;
    *(ushort8v*)&Bs[s0 * 512 + l * 8] = b0;
    *(ushort8v*)&Bs[s1 * 512 + l * 8] = b1;
    __syncthreads();
    bf16x8 af[4], bfr[4];
#pragma unroll
    for (int i = 0; i < 4; i++) af[i] = *(const bf16x8*)&As[(wm + i) * 512 + l * 8];
#pragma unroll
    for (int j = 0; j < 4; j++) bfr[j] = *(const bf16x8*)&Bs[(wn + j) * 512 + l * 8];
#pragma unroll
    for (int i = 0; i < 4; i++)
#pragma unroll
      for (int j = 0; j < 4; j++)
        acc[i][j] = __builtin_amdgcn_mfma_f32_16x16x32_bf16(af[i], bfr[j], acc[i][j], 0, 0, 0);
    __syncthreads();
  }

  int quad = l >> 4;
  // ----- C store -----
#pragma unroll
  for (int i = 0; i < 4; i++) {
    int r0 = brow0 + (wm + i) * 16 + quad * 4;
#pragma unroll
    for (int j = 0; j < 4; j++) {
      int col = bcol0 + (wn + j) * 16 + lm;
#pragma unroll
      for (int r = 0; r < 4; r++) {
        int row = r0 + r;
        if (row < NN) C[(size_t)row * 256 + col] = f2bf(acc[i][j][r]);
      }
    }
  }
  // ----- s/d epilogue: this wave owns head (bcol0>>6)+(wn>>2) for its rows -----
  float asv[4], adv[4];
#pragma unroll
  for (int j = 0; j < 4; j++) {
    int col = bcol0 + (wn + j) * 16 + lm;
    asv[j] = as_[col];
    adv[j] = ad_[col];
  }
  int head = (bcol0 >> 6) + (wn >> 2);
#pragma unroll
  for (int i = 0; i < 4; i++) {
#pragma unroll
    for (int r = 0; r < 4; r++) {
      float sp = acc[i][0][r] * asv[0] + acc[i][1][r] * asv[1] +
                 acc[i][2][r] * asv[2] + acc[i][3][r] * asv[3];
      float dp = acc[i][0][r] * adv[0] + acc[i][1][r] * adv[1] +
                 acc[i][2][r] * adv[2] + acc[i][3][r] * adv[3];
      sp += __shfl_xor(sp, 1); dp += __shfl_xor(dp, 1);
      sp += __shfl_xor(sp, 2); dp += __shfl_xor(dp, 2);
      sp += __shfl_xor(sp, 4); dp += __shfl_xor(dp, 4);
      sp += __shfl_xor(sp, 8); dp += __shfl_xor(dp, 8);
      if (lm == 0) {
        int row = brow0 + (wm + i) * 16 + quad * 4 + r;
        if (row < NN) {
          s_arr[row * HH + head] = sp;   // plain store: unique (row,head) per wave
          d_arr[row * HH + head] = dp;
        }
      }
    }
  }
}

// ---------- aggregation: one wave per node, all heads; fused edge softmax ----------
template <bool CONCAT>
__global__ __launch_bounds__(256) void agg_kernel(const ushort* __restrict__ hb,
                                                  const float* __restrict__ s_arr,
                                                  const float* __restrict__ d_arr,
                                                  const int* __restrict__ rowptr,
                                                  const int* __restrict__ csr_src,
                                                  const float* __restrict__ bias,
                                                  void* __restrict__ outp) {
  int w = __builtin_amdgcn_readfirstlane(threadIdx.x >> 6);
  int l = threadIdx.x & 63;
  int head = l >> 4;
  int n = blockIdx.x * 4 + w;
  int beg = rowptr[n], end = rowptr[n + 1];
  float dh = d_arr[n * HH + head];  // wave-uniform row, per-lane head select
  float a0 = 0.f, a1 = 0.f, a2 = 0.f, a3 = 0.f, den = 0.f;

  int i = beg;
  for (; i + 4 <= end; i += 4) {
    int s0 = csr_src[i], s1 = csr_src[i + 1], s2 = csr_src[i + 2], s3 = csr_src[i + 3];
    float e0 = s_arr[s0 * HH + head] + dh;
    float e1 = s_arr[s1 * HH + head] + dh;
    float e2 = s_arr[s2 * HH + head] + dh;
    float e3 = s_arr[s3 * HH + head] + dh;
    ushort4s h0 = *(const ushort4s*)(hb + (unsigned)(s0 * FDIM + l * 4));
    ushort4s h1 = *(const ushort4s*)(hb + (unsigned)(s1 * FDIM + l * 4));
    ushort4s h2 = *(const ushort4s*)(hb + (unsigned)(s2 * FDIM + l * 4));
    ushort4s h3 = *(const ushort4s*)(hb + (unsigned)(s3 * FDIM + l * 4));
    e0 = (e0 > 0.f) ? e0 : 0.2f * e0;  float w0 = __expf(e0);
    e1 = (e1 > 0.f) ? e1 : 0.2f * e1;  float w1 = __expf(e1);
    e2 = (e2 > 0.f) ? e2 : 0.2f * e2;  float w2 = __expf(e2);
    e3 = (e3 > 0.f) ? e3 : 0.2f * e3;  float w3 = __expf(e3);
    den += (w0 + w1) + (w2 + w3);
    a0 = fmaf(w0, bf2f(h0.x), a0); a1 = fmaf(w0, bf2f(h0.y), a1);
    a2 = fmaf(w0, bf2f(h0.z), a2); a3 = fmaf(w0, bf2f(h0.w), a3);
    a0 = fmaf(w1, bf2f(h1.x), a0); a1 = fmaf(w1, bf2f(h1.y), a1);
    a2 = fmaf(w1, bf2f(h1.z), a2); a3 = fmaf(w1, bf2f(h1.w), a3);
    a0 = fmaf(w2, bf2f(h2.x), a0); a1 = fmaf(w2, bf2f(h2.y), a1);
    a2 = fmaf(w2, bf2f(h2.z), a2); a3 = fmaf(w2, bf2f(h2.w), a3);
    a0 = fmaf(w3, bf2f(h3.x), a0); a1 = fmaf(w3, bf2f(h3.y), a1);
    a2 = fmaf(w3, bf2f(h3.z), a2); a3 = fmaf(w3, bf2f(h3.w), a3);
  }
  for (; i < end; i++) {
    int s0 = csr_src[i];
    float e0 = s_arr[s0 * HH + head] + dh;
    ushort4s h0 = *(const ushort4s*)(hb + (unsigned)(s0 * FDIM + l * 4));
    e0 = (e0 > 0.f) ? e0 : 0.2f * e0;
    float w0 = __expf(e0);
    den += w0;
    a0 = fmaf(w0, bf2f(h0.x), a0); a1 = fmaf(w0, bf2f(h0.y), a1);
    a2 = fmaf(w0, bf2f(h0.z), a2); a3 = fmaf(w0, bf2f(h0.w), a3);
  }
  float inv = 1.0f / den;  // self loop guarantees den > 0
  float r0 = a0 * inv, r1 = a1 * inv, r2 = a2 * inv, r3 = a3 * inv;

  if (CONCAT) {
    float4 bv = ((const float4*)bias)[l];
    ushort4s o;
    o.x = f2bf(r0 + bv.x); o.y = f2bf(r1 + bv.y);
    o.z = f2bf(r2 + bv.z); o.w = f2bf(r3 + bv.w);
    ((ushort4s*)outp)[(unsigned)(n * 64 + l)] = o;
  } else {
    // mean over heads: sum lanes {m, m+16, m+32, m+48}
    r0 += __shfl_xor(r0, 16); r1 += __shfl_xor(r1, 16);
    r2 += __shfl_xor(r2, 16); r3 += __shfl_xor(r3, 16);
    r0 += __shfl_xor(r0, 32); r1 += __shfl_xor(r1, 32);
    r2 += __shfl_xor(r2, 32); r3 += __shfl_xor(r3, 32);
    if (l < 16) {
      float4 bv = ((const float4*)bias)[l];
      float4 o;
      o.x = 0.25f * r0 + bv.x; o.y = 0.25f * r1 + bv.y;
      o.z = 0.25f * r2 + bv.z; o.w = 0.25f * r3 + bv.w;
      ((float4*)outp)[(unsigned)(n * 16 + l)] = o;
    }
  }
}

// ---------- GraphNorm ----------
// ushort4 loads (512B/wave/inst), LDS pre-reduction, 512 atomics per block
__global__ __launch_bounds__(256) void norm_reduce_bf(const ushort* __restrict__ xin,
                                                      float* colsum, float* colsumsq) {
  __shared__ float4 sm1[256], sm2[256];
  int t = threadIdx.x;
  int c4 = (t & 63) * 4;
  int rl = t >> 6;
  int r0 = blockIdx.x * 128;
  int r1 = min(NN, r0 + 128);
  float s0 = 0.f, s1 = 0.f, s2 = 0.f, s3 = 0.f;
  float q0 = 0.f, q1 = 0.f, q2 = 0.f, q3 = 0.f;
  for (int r = r0 + rl; r < r1; r += 4) {
    ushort4s v = *(const ushort4s*)(xin + (size_t)r * FDIM + c4);
    float f0 = bf2f(v.x), f1 = bf2f(v.y), f2 = bf2f(v.z), f3 = bf2f(v.w);
    s0 += f0; q0 += f0 * f0;
    s1 += f1; q1 += f1 * f1;
    s2 += f2; q2 += f2 * f2;
    s3 += f3; q3 += f3 * f3;
  }
  sm1[t] = float4{s0, s1, s2, s3};
  sm2[t] = float4{q0, q1, q2, q3};
  __syncthreads();
  if (t < 64) {
    float4 a = sm1[t], b = sm1[t + 64], c = sm1[t + 128], d = sm1[t + 192];
    atomicAdd(&colsum[c4 + 0], a.x + b.x + c.x + d.x);
    atomicAdd(&colsum[c4 + 1], a.y + b.y + c.y + d.y);
    atomicAdd(&colsum[c4 + 2], a.z + b.z + c.z + d.z);
    atomicAdd(&colsum[c4 + 3], a.w + b.w + c.w + d.w);
    float4 e = sm2[t], f = sm2[t + 64], g = sm2[t + 128], h = sm2[t + 192];
    atomicAdd(&colsumsq[c4 + 0], e.x + f.x + g.x + h.x);
    atomicAdd(&colsumsq[c4 + 1], e.y + f.y + g.y + h.y);
    atomicAdd(&colsumsq[c4 + 2], e.z + f.z + g.z + h.z);
    atomicAdd(&colsumsq[c4 + 3], e.w + f.w + g.w + h.w);
  }
}

__global__ __launch_bounds__(256) void norm_reduce_f32(const float* __restrict__ xin,
                                                       float* colsum, float* colsumsq) {
  int f = threadIdx.x & (CC - 1);
  int rl = threadIdx.x / CC;
  int r0 = blockIdx.x * 128;
  int r1 = min(NN, r0 + 128);
  float s1 = 0.f, s2 = 0.f;
  for (int r = r0 + rl; r < r1; r += 4) {
    float v = xin[(size_t)r * CC + f];
    s1 += v; s2 += v * v;
  }
  atomicAdd(&colsum[f], s1);
  atomicAdd(&colsumsq[f], s2);
}

// finalize folded in: each block recomputes scale/shift, then grid-stride apply
__global__ __launch_bounds__(256) void norm_apply_bf(const ushort* __restrict__ in,
                                                     ushort* __restrict__ outb,
                                                     const float* __restrict__ colsum,
                                                     const float* __restrict__ colsumsq,
                                                     const float* __restrict__ ga,
                                                     const float* __restrict__ gw,
                                                     const float* __restrict__ gb) {
  __shared__ float sc[FDIM], sh[FDIM];
  int t = threadIdx.x;
  {
    const float invn = 1.0f / (float)NN;
    float mu = colsum[t] * invn;
    float ex2 = colsumsq[t] * invn;
    float a = ga[t];
    float var = fmaxf(ex2 - (2.f * a - a * a) * mu * mu, 0.f);
    float s = gw[t] * rsqrtf(var + 1e-5f);
    sc[t] = s; sh[t] = gb[t] - s * a * mu;
  }
  __syncthreads();
  const int total = NN * FDIM / 4;
  for (int i = blockIdx.x * 256 + t; i < total; i += gridDim.x * 256) {
    int f0 = (i * 4) & (FDIM - 1);
    ushort4s v = ((const ushort4s*)in)[i];
    float y0 = sc[f0 + 0] * bf2f(v.x) + sh[f0 + 0];
    float y1 = sc[f0 + 1] * bf2f(v.y) + sh[f0 + 1];
    float y2 = sc[f0 + 2] * bf2f(v.z) + sh[f0 + 2];
    float y3 = sc[f0 + 3] * bf2f(v.w) + sh[f0 + 3];
    ushort4s o;
    o.x = f2bf((y0 > 0.f) ? y0 : 0.01f * y0);
    o.y = f2bf((y1 > 0.f) ? y1 : 0.01f * y1);
    o.z = f2bf((y2 > 0.f) ? y2 : 0.01f * y2);
    o.w = f2bf((y3 > 0.f) ? y3 : 0.01f * y3);
    ((ushort4s*)outb)[i] = o;
  }
}

// ---------- MLP 64->32->16->2 with fused GraphNorm+LeakyReLU on input ----------
__global__ __launch_bounds__(256) void mlp_kernel(const float* __restrict__ xin,
                                                  const float* __restrict__ colsum,
                                                  const float* __restrict__ colsumsq,
                                                  const float* __restrict__ ga,
                                                  const float* __restrict__ gw,
                                                  const float* __restrict__ gb,
                                                  const float* mW0, const float* mb0,
                                                  const float* mW1, const float* mb1,
                                                  const float* mW2, const float* mb2,
                                                  float* __restrict__ out) {
  __shared__ float W0s[64 * 32];
  __shared__ float W1s[32 * 16];
  __shared__ float W2s[16 * 2];
  __shared__ float b0s[32], b1s[16], b2s[2];
  __shared__ float sc[CC], sh[CC];
  int t = threadIdx.x;
  for (int i = t; i < 2048; i += 256) W0s[i] = mW0[i];
  for (int i = t; i < 512; i += 256) W1s[i] = mW1[i];
  if (t < 32) { W2s[t] = mW2[t]; b0s[t] = mb0[t]; }
  if (t < 16) b1s[t] = mb1[t];
  if (t < 2) b2s[t] = mb2[t];
  if (t < CC) {
    const float invn = 1.0f / (float)NN;
    float mu = colsum[t] * invn;
    float ex2 = colsumsq[t] * invn;
    float a = ga[t];
    float var = fmaxf(ex2 - (2.f * a - a * a) * mu * mu, 0.f);
    float s = gw[t] * rsqrtf(var + 1e-5f);
    sc[t] = s; sh[t] = gb[t] - s * a * mu;
  }
  __syncthreads();
  int node = blockIdx.x * 256 + t;
  if (node >= NN) return;
  float in[64];
  const float* xr = xin + (size_t)node * 64;
#pragma unroll
  for (int k = 0; k < 64; k++) {
    float y = sc[k] * xr[k] + sh[k];
    in[k] = (y > 0.f) ? y : 0.01f * y;   // GraphNorm + LeakyReLU(0.01) fused
  }
  float h1[32];
#pragma unroll
  for (int j = 0; j < 32; j++) h1[j] = b0s[j];
#pragma unroll
  for (int k = 0; k < 64; k++) {
    float v = in[k];
#pragma unroll
    for (int j = 0; j < 32; j++) h1[j] += v * W0s[k * 32 + j];
  }
#pragma unroll
  for (int j = 0; j < 32; j++) h1[j] = fmaxf(h1[j], 0.f);
  float h2[16];
#pragma unroll
  for (int j = 0; j < 16; j++) h2[j] = b1s[j];
#pragma unroll
  for (int k = 0; k < 32; k++) {
    float v = h1[k];
#pragma unroll
    for (int j = 0; j < 16; j++) h2[j] += v * W1s[k * 16 + j];
  }
#pragma unroll
  for (int j = 0; j < 16; j++) h2[j] = fmaxf(h2[j], 0.f);
  float o0 = b2s[0], o1 = b2s[1];
#pragma unroll
  for (int k = 0; k < 16; k++) {
    o0 += h2[k] * W2s[k * 2 + 0];
    o1 += h2[k] * W2s[k * 2 + 1];
  }
  out[(size_t)node * 2 + 0] = o0;
  out[(size_t)node * 2 + 1] = o1;
}

extern "C" void kernel_launch(void* const* d_in, const int* in_sizes, int n_in,
                              void* d_out, int out_size, void* d_ws, size_t ws_size,
                              hipStream_t stream) {
  const float* x = (const float*)d_in[0];
  const void* ei = d_in[1];
  const float* W[3]   = {(const float*)d_in[2],  (const float*)d_in[9],  (const float*)d_in[16]};
  const float* as_[3] = {(const float*)d_in[3],  (const float*)d_in[10], (const float*)d_in[17]};
  const float* ad_[3] = {(const float*)d_in[4],  (const float*)d_in[11], (const float*)d_in[18]};
  const float* b_[3]  = {(const float*)d_in[5],  (const float*)d_in[12], (const float*)d_in[19]};
  const float* gw[3]  = {(const float*)d_in[6],  (const float*)d_in[13], (const float*)d_in[20]};
  const float* gb[3]  = {(const float*)d_in[7],  (const float*)d_in[14], (const float*)d_in[21]};
  const float* ga[3]  = {(const float*)d_in[8],  (const float*)d_in[15], (const float*)d_in[22]};
  const float* mW0 = (const float*)d_in[23];
  const float* mb0 = (const float*)d_in[24];
  const float* mW1 = (const float*)d_in[25];
  const float* mb1 = (const float*)d_in[26];
  const float* mW2 = (const float*)d_in[27];
  const float* mb2 = (const float*)d_in[28];
  float* out = (float*)d_out;

  char* ws = (char*)d_ws;
  size_t off = 0;
  auto take = [&](size_t bytes) -> char* {
    char* p = ws + off;
    off = (off + bytes + 255) & ~(size_t)255;
    return p;
  };
  ushort* hb    = (ushort*)take((size_t)NN * FDIM * 2);
  ushort* yb    = (ushort*)take((size_t)NN * FDIM * 2);
  ushort* aggb  = (ushort*)take((size_t)NN * FDIM * 2);
  float* bufD   = (float*)take((size_t)NN * CC * 4);
  ushort* Wt[3];
  for (int i = 0; i < 3; i++) Wt[i] = (ushort*)take((size_t)256 * 256 * 2);
  float* s_arr  = (float*)take((size_t)NN * HH * 4);
  float* d_arr  = (float*)take((size_t)NN * HH * 4);
  float* colsum   = (float*)take(1024);   // colsum+colsumsq contiguous: one memset
  float* colsumsq = (float*)take(1024);
  int* deg      = (int*)take((size_t)NN * 4);
  int* cursor   = (int*)take((size_t)NN * 4);
  int* rowptr   = (int*)take((size_t)(NN + 1) * 4);
  int* csr_src  = (int*)take((size_t)ET * 4);
  int* bsum     = (int*)take(512);
  int* boff     = (int*)take(512);
  int* flag     = (int*)take(256);

  // CSR build (reused by all 3 layers)
  hipMemsetAsync(deg, 0, (size_t)NN * 4, stream);
  detect_kernel<<<1, 256, 0, stream>>>((const unsigned int*)ei, flag);
  degree_kernel<<<(ET + 255) / 256, 256, 0, stream>>>(ei, flag, deg);
  scan1_kernel<<<SCAN_NB, SCAN_BLK, 0, stream>>>(deg, rowptr, bsum);
  scan2_kernel<<<1, 128, 0, stream>>>(bsum, boff, rowptr);
  scan3_kernel<<<SCAN_NB, SCAN_BLK, 0, stream>>>(rowptr, cursor, boff);
  fill_kernel<<<(ET + 255) / 256, 256, 0, stream>>>(ei, flag, cursor, csr_src);

  // weight prep (x is consumed in f32 directly by layer-0 gemm)
  conv_w_kernel<<<dim3(256, 3), 256, 0, stream>>>(W[0], W[1], W[2], Wt[0], Wt[1], Wt[2]);

  const void* lin = (const void*)x;
  for (int L = 0; L < 3; L++) {
    if (L == 0)
      gemm_bf16<1><<<dim3((NN + 127) / 128, 2), 256, 0, stream>>>(lin, Wt[L], hb,
                                                                  as_[L], ad_[L], s_arr, d_arr);
    else
      gemm_bf16<0><<<dim3((NN + 127) / 128, 2), 256, 0, stream>>>(lin, Wt[L], hb,
                                                                  as_[L], ad_[L], s_arr, d_arr);
    hipMemsetAsync(colsum, 0, 2048, stream);
    if (L < 2) {
      agg_kernel<true><<<NN / 4, 256, 0, stream>>>(hb, s_arr, d_arr, rowptr, csr_src, b_[L], aggb);
      norm_reduce_bf<<<(NN + 127) / 128, 256, 0, stream>>>(aggb, colsum, colsumsq);
      norm_apply_bf<<<1024, 256, 0, stream>>>(aggb, yb, colsum, colsumsq, ga[L], gw[L], gb[L]);
      lin = (const void*)yb;
    } else {
      agg_kernel<false><<<NN / 4, 256, 0, stream>>>(hb, s_arr, d_arr, rowptr, csr_src, b_[L], bufD);
      norm_reduce_f32<<<(NN + 127) / 128, 256, 0, stream>>>(bufD, colsum, colsumsq);
    }
  }
  mlp_kernel<<<(NN + 255) / 256, 256, 0, stream>>>(bufD, colsum, colsumsq,
                                                   ga[2], gw[2], gb[2],
                                                   mW0, mb0, mW1, mb1, mW2, mb2, out);
}